// Round 19
// baseline (66.741 us; speedup 1.0000x reference)
//
#include <hip/hip_runtime.h>

#define NN 50
#define D 64
#define GRP 10

typedef unsigned int uint32;
typedef unsigned short ushort16;

__device__ __forceinline__ float wave_sum64(float x) {
#pragma unroll
  for (int off = 32; off > 0; off >>= 1)
    x += __shfl_xor(x, off, 64);
  return x;
}

__device__ __forceinline__ float readlane_f(float v, int l) {
  return __uint_as_float(__builtin_amdgcn_readlane(__float_as_uint(v), l));
}

__device__ __forceinline__ ushort16 f32_to_bf16(float f) {
  uint32 u = __float_as_uint(f);
  u += 0x7FFF + ((u >> 16) & 1);          // round-to-nearest-even
  return (ushort16)(u >> 16);
}
__device__ __forceinline__ float bf16_to_f32(ushort16 h) {
  return __uint_as_float(((uint32)h) << 16);
}

// ============ P: proj[e] = dot(ent[e], Wn); ent_bf = bf16(ent) ==============
__global__ __launch_bounds__(256, 4) void ent_proj(
    const float* __restrict__ ent_tab, const float* __restrict__ attn_W,
    float* __restrict__ proj, ushort16* __restrict__ ent_bf, int rows)
{
  const int  lane = threadIdx.x & 63;
  const long wave = (long)blockIdx.x * 4 + (threadIdx.x >> 6);
  const long base = wave * GRP;
  if (base >= rows) return;
  const float Wn = attn_W[D + lane];
  float v[GRP];
#pragma unroll
  for (int i = 0; i < GRP; ++i) {
    long r = base + i; if (r > rows - 1) r = rows - 1;
    v[i] = ent_tab[r * D + lane];           // coalesced, contiguous rows
  }
  float s[GRP];
#pragma unroll
  for (int i = 0; i < GRP; ++i)
    s[i] = wave_sum64(v[i] * Wn);           // 10 independent butterfly chains
#pragma unroll
  for (int i = 0; i < GRP; ++i) {
    const long r = base + i;
    if (r < rows) ent_bf[r * D + lane] = f32_to_bf16(v[i]);
  }
  if (lane == 0) {
#pragma unroll
    for (int i = 0; i < GRP; ++i)
      if (base + i < rows) proj[base + i] = s[i];
  }
}

// ============ A: attention -> na rows in ws (R10-proven, E=1, max TLP) ======
__device__ __forceinline__ void load_grp_bf(float (&buf)[GRP],
                                            const int* __restrict__ adjb,
                                            const ushort16* __restrict__ ent_bf,
                                            int g, int lane) {
#pragma unroll
  for (int i = 0; i < GRP; ++i) {
    int t = adjb[g * GRP + i];              // wave-uniform -> s_load
    t = t < 0 ? 0 : t;
    buf[i] = bf16_to_f32(ent_bf[(long)t * D + lane]);   // 128B coalesced row
  }
}

__device__ __forceinline__ void acc_grp(const float (&buf)[GRP], float e, int g,
                                        float& na0, float& na1) {
#pragma unroll
  for (int i = 0; i < GRP; ++i) {
    const float w = readlane_f(e, g * GRP + i);   // compile-time lane index
    if (i & 1) na1 = fmaf(w, buf[i], na1);
    else       na0 = fmaf(w, buf[i], na0);
  }
}

__global__ __launch_bounds__(256, 4) void kgat_attn(
    const int* __restrict__ item_idx, const int* __restrict__ adj,
    const float* __restrict__ item_tab,
    const ushort16* __restrict__ ent_bf, const float* __restrict__ proj,
    const float* __restrict__ attn_W, const float* __restrict__ attn_b,
    float* __restrict__ naws, int B)
{
  const int lane = threadIdx.x & 63;
  const int wv   = threadIdx.x >> 6;
  const int b    = blockIdx.x * 4 + wv;
  if (b >= B) return;

  const int* adjb = adj + (long)b * NN;

  // issue first two gather groups before score math (overlap latency)
  float A[GRP], Bv[GRP];
  load_grp_bf(A,  adjb, ent_bf, 0, lane);
  load_grp_bf(Bv, adjb, ent_bf, 1, lane);

  const float item = item_tab[(long)item_idx[b] * D + lane];
  const float base = wave_sum64(item * attn_W[lane]) + attn_b[0];  // uniform

  // scores: lane n gathers proj[adj[n]] (800KB, L2-hot); fixed-max softmax
  const int myn = lane < NN ? lane : NN - 1;
  int mi = adjb[myn]; mi = mi < 0 ? 0 : mi;
  float s = proj[mi] + base;
  s = s > 0.f ? s : 0.2f * s;                     // leaky_relu(0.2)
  const float e = (lane < NN) ? __expf(s - 8.0f) : 0.f;
  const float denom = wave_sum64(e);

  // weighted sum: proven double-buffered coalesced row groups (bf16 rows)
  float na0 = 0.f, na1 = 0.f;
  acc_grp(A,  e, 0, na0, na1);
  load_grp_bf(A,  adjb, ent_bf, 2, lane);
  acc_grp(Bv, e, 1, na0, na1);
  load_grp_bf(Bv, adjb, ent_bf, 3, lane);
  acc_grp(A,  e, 2, na0, na1);
  load_grp_bf(A,  adjb, ent_bf, 4, lane);
  acc_grp(Bv, e, 3, na0, na1);
  acc_grp(A,  e, 4, na0, na1);

  naws[(long)b * D + lane] = (na0 + na1) / denom;
}

// ====== M: joint MLP, 4 elements/wave, readlane broadcast (NO LDS/DS) =======
__global__ __launch_bounds__(256, 4) void kgat_mlp4r(
    const int* __restrict__ user_idx, const int* __restrict__ item_idx,
    const float* __restrict__ user_tab, const float* __restrict__ item_tab,
    const float* __restrict__ naws,
    const float* __restrict__ W1, const float* __restrict__ b1,
    const float* __restrict__ W2, const float* __restrict__ b2,
    const float* __restrict__ cW, const float* __restrict__ cb,
    const float* __restrict__ oW, const float* __restrict__ ob,
    float* __restrict__ out, int B)
{
  const int lane = threadIdx.x & 63;
  const int wv   = threadIdx.x >> 6;
  const int b0   = (blockIdx.x * 4 + wv) * 4;
  if (b0 >= B) return;

  const int bA = b0 + 0 < B ? b0 + 0 : B - 1;
  const int bB = b0 + 1 < B ? b0 + 1 : B - 1;
  const int bC = b0 + 2 < B ? b0 + 2 : B - 1;
  const int bD = b0 + 3 < B ? b0 + 3 : B - 1;

  // coalesced 256B row loads (lane = dim)
  const float naA = naws[(long)bA * D + lane];
  const float naB = naws[(long)bB * D + lane];
  const float naC = naws[(long)bC * D + lane];
  const float naD = naws[(long)bD * D + lane];
  const float itA = item_tab[(long)item_idx[bA] * D + lane];
  const float itB = item_tab[(long)item_idx[bB] * D + lane];
  const float itC = item_tab[(long)item_idx[bC] * D + lane];
  const float itD = item_tab[(long)item_idx[bD] * D + lane];
  const float usA = user_tab[(long)user_idx[bA] * D + lane];
  const float usB = user_tab[(long)user_idx[bB] * D + lane];
  const float usC = user_tab[(long)user_idx[bC] * D + lane];
  const float usD = user_tab[(long)user_idx[bD] * D + lane];

  // ---- h = relu(na @ W1 + b1): broadcast via readlane (VALU pipe, no DS);
  //      one weight column load feeds all 4 elements ----
  const float b1v = b1[lane];
  float hA0 = b1v, hA1 = 0.f, hB0 = b1v, hB1 = 0.f;
  float hC0 = b1v, hC1 = 0.f, hD0 = b1v, hD1 = 0.f;
#pragma unroll
  for (int k = 0; k < D; k += 2) {
    const float w0 = W1[(k + 0) * D + lane];
    const float w1 = W1[(k + 1) * D + lane];
    hA0 = fmaf(readlane_f(naA, k + 0), w0, hA0);
    hA1 = fmaf(readlane_f(naA, k + 1), w1, hA1);
    hB0 = fmaf(readlane_f(naB, k + 0), w0, hB0);
    hB1 = fmaf(readlane_f(naB, k + 1), w1, hB1);
    hC0 = fmaf(readlane_f(naC, k + 0), w0, hC0);
    hC1 = fmaf(readlane_f(naC, k + 1), w1, hC1);
    hD0 = fmaf(readlane_f(naD, k + 0), w0, hD0);
    hD1 = fmaf(readlane_f(naD, k + 1), w1, hD1);
  }
  const float hA = fmaxf(hA0 + hA1, 0.f);
  const float hB = fmaxf(hB0 + hB1, 0.f);
  const float hC = fmaxf(hC0 + hC1, 0.f);
  const float hD = fmaxf(hD0 + hD1, 0.f);

  // ---- r = h @ W2 + b2 ----
  const float b2v = b2[lane];
  float rA0 = b2v, rA1 = 0.f, rB0 = b2v, rB1 = 0.f;
  float rC0 = b2v, rC1 = 0.f, rD0 = b2v, rD1 = 0.f;
#pragma unroll
  for (int k = 0; k < D; k += 2) {
    const float w0 = W2[(k + 0) * D + lane];
    const float w1 = W2[(k + 1) * D + lane];
    rA0 = fmaf(readlane_f(hA, k + 0), w0, rA0);
    rA1 = fmaf(readlane_f(hA, k + 1), w1, rA1);
    rB0 = fmaf(readlane_f(hB, k + 0), w0, rB0);
    rB1 = fmaf(readlane_f(hB, k + 1), w1, rB1);
    rC0 = fmaf(readlane_f(hC, k + 0), w0, rC0);
    rC1 = fmaf(readlane_f(hC, k + 1), w1, rC1);
    rD0 = fmaf(readlane_f(hD, k + 0), w0, rD0);
    rD1 = fmaf(readlane_f(hD, k + 1), w1, rD1);
  }
  const float rA = rA0 + rA1;
  const float rB = rB0 + rB1;
  const float rC = rC0 + rC1;
  const float rD = rD0 + rD1;

  // ---- f = relu([item, r] @ cW + cb) ----
  const float cbv = cb[lane];
  float fA0 = cbv, fA1 = 0.f, fB0 = cbv, fB1 = 0.f;
  float fC0 = cbv, fC1 = 0.f, fD0 = cbv, fD1 = 0.f;
#pragma unroll
  for (int k = 0; k < D; k += 2) {
    const float w0 = cW[(k + 0) * D + lane];
    const float w1 = cW[(k + 1) * D + lane];
    fA0 = fmaf(readlane_f(itA, k + 0), w0, fA0);
    fA1 = fmaf(readlane_f(itA, k + 1), w1, fA1);
    fB0 = fmaf(readlane_f(itB, k + 0), w0, fB0);
    fB1 = fmaf(readlane_f(itB, k + 1), w1, fB1);
    fC0 = fmaf(readlane_f(itC, k + 0), w0, fC0);
    fC1 = fmaf(readlane_f(itC, k + 1), w1, fC1);
    fD0 = fmaf(readlane_f(itD, k + 0), w0, fD0);
    fD1 = fmaf(readlane_f(itD, k + 1), w1, fD1);
  }
#pragma unroll
  for (int k = 0; k < D; k += 2) {
    const float w0 = cW[(D + k + 0) * D + lane];
    const float w1 = cW[(D + k + 1) * D + lane];
    fA0 = fmaf(readlane_f(rA, k + 0), w0, fA0);
    fA1 = fmaf(readlane_f(rA, k + 1), w1, fA1);
    fB0 = fmaf(readlane_f(rB, k + 0), w0, fB0);
    fB1 = fmaf(readlane_f(rB, k + 1), w1, fB1);
    fC0 = fmaf(readlane_f(rC, k + 0), w0, fC0);
    fC1 = fmaf(readlane_f(rC, k + 1), w1, fC1);
    fD0 = fmaf(readlane_f(rD, k + 0), w0, fD0);
    fD1 = fmaf(readlane_f(rD, k + 1), w1, fD1);
  }
  const float fA = fmaxf(fA0 + fA1, 0.f);
  const float fB = fmaxf(fB0 + fB1, 0.f);
  const float fC = fmaxf(fC0 + fC1, 0.f);
  const float fD = fmaxf(fD0 + fD1, 0.f);

  // ---- score = dot([user, f], oW) + ob ----
  const float oWu = oW[lane];
  const float oWf = oW[D + lane];
  const float ob0 = ob[0];
  const float scA = wave_sum64(fmaf(usA, oWu, fA * oWf));
  const float scB = wave_sum64(fmaf(usB, oWu, fB * oWf));
  const float scC = wave_sum64(fmaf(usC, oWu, fC * oWf));
  const float scD = wave_sum64(fmaf(usD, oWu, fD * oWf));
  if (lane == 0) {
    out[bA] = scA + ob0;
    if (bB != bA) out[bB] = scB + ob0;
    if (bC != bB) out[bC] = scC + ob0;
    if (bD != bC) out[bD] = scD + ob0;
  }
}

// ================= fallback: exact R3 kernel (small/no workspace) ===========
__device__ __forceinline__ void load_grp(float (&buf)[GRP],
                                         const int* __restrict__ adjb,
                                         const float* __restrict__ ent_tab,
                                         int g, int lane) {
#pragma unroll
  for (int i = 0; i < GRP; ++i) {
    int t = adjb[g * GRP + i];
    t = t < 0 ? 0 : t;
    buf[i] = ent_tab[(long)t * D + lane];
  }
}

__device__ __forceinline__ void proc_grp(const float (&buf)[GRP],
                                         float Wn, float base,
                                         float& l0, float& l1, float& na) {
  float ex[GRP];
#pragma unroll
  for (int i = 0; i < GRP; ++i) {
    float t = wave_sum64(buf[i] * Wn) + base;
    t = t > 0.f ? t : 0.2f * t;
    ex[i] = __expf(t - 8.0f);
  }
#pragma unroll
  for (int i = 0; i < GRP; ++i) {
    if (i & 1) l1 += ex[i]; else l0 += ex[i];
    na = fmaf(ex[i], buf[i], na);
  }
}

__global__ __launch_bounds__(256, 4) void kgat_r3(
    const int* __restrict__ user_idx, const int* __restrict__ item_idx,
    const int* __restrict__ adj,
    const float* __restrict__ user_tab, const float* __restrict__ item_tab,
    const float* __restrict__ ent_tab,
    const float* __restrict__ attn_W, const float* __restrict__ attn_b,
    const float* __restrict__ W1, const float* __restrict__ b1,
    const float* __restrict__ W2, const float* __restrict__ b2,
    const float* __restrict__ cW, const float* __restrict__ cb,
    const float* __restrict__ oW, const float* __restrict__ ob,
    float* __restrict__ out, int B)
{
  const int lane = threadIdx.x & 63;
  const int wv   = threadIdx.x >> 6;
  const int b    = blockIdx.x * 4 + wv;
  if (b >= B) return;

  const float user = user_tab[(long)user_idx[b] * D + lane];
  const float oWu  = oW[lane];
  const float oWf  = oW[D + lane];
  const float item = item_tab[(long)item_idx[b] * D + lane];
  const float Wi   = attn_W[lane];
  const float Wn   = attn_W[D + lane];
  const float base = wave_sum64(item * Wi) + attn_b[0];
  const int* adjb = adj + b * NN;

  float na = 0.f, l0 = 0.f, l1 = 0.f;
  float A[GRP], Bv[GRP];
  load_grp(A,  adjb, ent_tab, 0, lane);
  load_grp(Bv, adjb, ent_tab, 1, lane);
  proc_grp(A,  Wn, base, l0, l1, na);
  load_grp(A,  adjb, ent_tab, 2, lane);
  proc_grp(Bv, Wn, base, l0, l1, na);
  load_grp(Bv, adjb, ent_tab, 3, lane);
  proc_grp(A,  Wn, base, l0, l1, na);
  load_grp(A,  adjb, ent_tab, 4, lane);
  proc_grp(Bv, Wn, base, l0, l1, na);
  proc_grp(A,  Wn, base, l0, l1, na);
  na /= (l0 + l1);

  float h0 = b1[lane], h1 = 0.f, h2 = 0.f, h3 = 0.f;
#pragma unroll
  for (int d = 0; d < D; d += 4) {
    h0 = fmaf(readlane_f(na, d + 0), W1[(d + 0) * D + lane], h0);
    h1 = fmaf(readlane_f(na, d + 1), W1[(d + 1) * D + lane], h1);
    h2 = fmaf(readlane_f(na, d + 2), W1[(d + 2) * D + lane], h2);
    h3 = fmaf(readlane_f(na, d + 3), W1[(d + 3) * D + lane], h3);
  }
  const float h = fmaxf((h0 + h1) + (h2 + h3), 0.f);

  float r0 = b2[lane], r1 = 0.f, r2 = 0.f, r3 = 0.f;
#pragma unroll
  for (int d = 0; d < D; d += 4) {
    r0 = fmaf(readlane_f(h, d + 0), W2[(d + 0) * D + lane], r0);
    r1 = fmaf(readlane_f(h, d + 1), W2[(d + 1) * D + lane], r1);
    r2 = fmaf(readlane_f(h, d + 2), W2[(d + 2) * D + lane], r2);
    r3 = fmaf(readlane_f(h, d + 3), W2[(d + 3) * D + lane], r3);
  }
  const float r = (r0 + r1) + (r2 + r3);

  float f0 = cb[lane], f1 = 0.f, f2 = 0.f, f3 = 0.f;
#pragma unroll
  for (int k = 0; k < D; k += 4) {
    f0 = fmaf(readlane_f(item, k + 0), cW[(k + 0) * D + lane], f0);
    f1 = fmaf(readlane_f(item, k + 1), cW[(k + 1) * D + lane], f1);
    f2 = fmaf(readlane_f(item, k + 2), cW[(k + 2) * D + lane], f2);
    f3 = fmaf(readlane_f(item, k + 3), cW[(k + 3) * D + lane], f3);
  }
#pragma unroll
  for (int k = 0; k < D; k += 4) {
    f0 = fmaf(readlane_f(r, k + 0), cW[(D + k + 0) * D + lane], f0);
    f1 = fmaf(readlane_f(r, k + 1), cW[(D + k + 1) * D + lane], f1);
    f2 = fmaf(readlane_f(r, k + 2), cW[(D + k + 2) * D + lane], f2);
    f3 = fmaf(readlane_f(r, k + 3), cW[(D + k + 3) * D + lane], f3);
  }
  const float f = fmaxf((f0 + f1) + (f2 + f3), 0.f);

  const float sc = wave_sum64(fmaf(user, oWu, f * oWf));
  if (lane == 0) out[b] = sc + ob[0];
}

extern "C" void kernel_launch(void* const* d_in, const int* in_sizes, int n_in,
                              void* d_out, int out_size, void* d_ws, size_t ws_size,
                              hipStream_t stream) {
  const int*   user_idx = (const int*)d_in[0];
  const int*   item_idx = (const int*)d_in[1];
  const int*   adj      = (const int*)d_in[2];
  const float* user_tab = (const float*)d_in[3];
  const float* item_tab = (const float*)d_in[4];
  const float* ent_tab  = (const float*)d_in[5];
  const float* attn_W   = (const float*)d_in[6];
  const float* attn_b   = (const float*)d_in[7];
  const float* W1       = (const float*)d_in[8];
  const float* b1       = (const float*)d_in[9];
  const float* W2       = (const float*)d_in[10];
  const float* b2       = (const float*)d_in[11];
  const float* cW       = (const float*)d_in[12];
  const float* cb       = (const float*)d_in[13];
  const float* oW       = (const float*)d_in[14];
  const float* ob       = (const float*)d_in[15];
  float* out = (float*)d_out;

  const int B    = in_sizes[0];
  const int rows = in_sizes[5] / D;               // entity count

  // ws layout: [proj f32][ent_bf bf16][naws f32], 256B-aligned sections
  const size_t off_bf = ((size_t)rows * 4 + 255) & ~(size_t)255;
  const size_t off_na = (off_bf + (size_t)rows * D * 2 + 255) & ~(size_t)255;
  const size_t need   = off_na + (size_t)B * D * 4;

  if (ws_size >= need) {
    float*    proj   = (float*)d_ws;
    ushort16* ent_bf = (ushort16*)((char*)d_ws + off_bf);
    float*    naws   = (float*)((char*)d_ws + off_na);
    const int waves   = (rows + GRP - 1) / GRP;
    const int pblocks = (waves + 3) / 4;
    const int ablocks = (B + 3) / 4;              // attention: 1 elem/wave
    const int mblocks = (B + 15) / 16;            // MLP: 4 elems/wave
    ent_proj<<<pblocks, 256, 0, stream>>>(ent_tab, attn_W, proj, ent_bf, rows);
    kgat_attn<<<ablocks, 256, 0, stream>>>(item_idx, adj, item_tab, ent_bf,
                                           proj, attn_W, attn_b, naws, B);
    kgat_mlp4r<<<mblocks, 256, 0, stream>>>(user_idx, item_idx, user_tab,
                                            item_tab, naws, W1, b1, W2, b2,
                                            cW, cb, oW, ob, out, B);
  } else {
    const int blocks = (B + 3) / 4;
    kgat_r3<<<blocks, 256, 0, stream>>>(user_idx, item_idx, adj,
                                        user_tab, item_tab, ent_tab,
                                        attn_W, attn_b, W1, b1, W2, b2,
                                        cW, cb, oW, ob, out, B);
  }
}

// Round 20
// 57.634 us; speedup vs baseline: 1.1580x; 1.1580x over previous
//
#include <hip/hip_runtime.h>

#define NN 50
#define D 64
#define GRP 10

typedef unsigned int uint32;
typedef unsigned short ushort16;

__device__ __forceinline__ float wave_sum64(float x) {
#pragma unroll
  for (int off = 32; off > 0; off >>= 1)
    x += __shfl_xor(x, off, 64);
  return x;
}

__device__ __forceinline__ float readlane_f(float v, int l) {
  return __uint_as_float(__builtin_amdgcn_readlane(__float_as_uint(v), l));
}

__device__ __forceinline__ ushort16 f32_to_bf16(float f) {
  uint32 u = __float_as_uint(f);
  u += 0x7FFF + ((u >> 16) & 1);          // round-to-nearest-even
  return (ushort16)(u >> 16);
}

// ============ P: proj[e] = dot(ent[e], Wn); ent_bf = bf16(ent) ==============
__global__ __launch_bounds__(256, 4) void ent_proj(
    const float* __restrict__ ent_tab, const float* __restrict__ attn_W,
    float* __restrict__ proj, ushort16* __restrict__ ent_bf, int rows)
{
  const int  lane = threadIdx.x & 63;
  const long wave = (long)blockIdx.x * 4 + (threadIdx.x >> 6);
  const long base = wave * GRP;
  if (base >= rows) return;
  const float Wn = attn_W[D + lane];
  float v[GRP];
#pragma unroll
  for (int i = 0; i < GRP; ++i) {
    long r = base + i; if (r > rows - 1) r = rows - 1;
    v[i] = ent_tab[r * D + lane];           // coalesced, contiguous rows
  }
  float s[GRP];
#pragma unroll
  for (int i = 0; i < GRP; ++i)
    s[i] = wave_sum64(v[i] * Wn);           // 10 independent butterfly chains
#pragma unroll
  for (int i = 0; i < GRP; ++i) {
    const long r = base + i;
    if (r < rows) ent_bf[r * D + lane] = f32_to_bf16(v[i]);
  }
  if (lane == 0) {
#pragma unroll
    for (int i = 0; i < GRP; ++i)
      if (base + i < rows) proj[base + i] = s[i];
  }
}

// ===== A: attention, paired-row gathers (2 rows / wave-load, 4B / lane) =====
// Lane layout: sub = lane&31 owns dims {2*sub, 2*sub+1}; half = lane>>5
// selects even(0)/odd(1) neighbor of each pair. 25 pair-loads replace 50
// row-loads; buffers are 5 uints/group (half the VGPR of the float version).
#define PGRP 5

__device__ __forceinline__ void load_pair_grp(uint32 (&buf)[PGRP],
                                              const int* __restrict__ adjb,
                                              const uint32* __restrict__ ent32,
                                              int g, int half, int sub) {
#pragma unroll
  for (int i = 0; i < PGRP; ++i) {
    const int p = g * PGRP + i;
    int t0 = adjb[2 * p + 0]; t0 = t0 < 0 ? 0 : t0;   // wave-uniform -> s_load
    int t1 = adjb[2 * p + 1]; t1 = t1 < 0 ? 0 : t1;
    const int t = half ? t1 : t0;
    buf[i] = ent32[(size_t)t * 32 + sub];   // 4B/lane, 2 rows per instruction
  }
}

__device__ __forceinline__ void acc_pair_grp(const uint32 (&buf)[PGRP],
                                             float e, int g, int half,
                                             float& lo0, float& lo1,
                                             float& hi0, float& hi1) {
#pragma unroll
  for (int i = 0; i < PGRP; ++i) {
    const int p = g * PGRP + i;
    const float w0 = readlane_f(e, 2 * p + 0);
    const float w1 = readlane_f(e, 2 * p + 1);
    const float w  = half ? w1 : w0;
    const float lo = __uint_as_float(buf[i] << 16);          // bf16 dim 2*sub
    const float hi = __uint_as_float(buf[i] & 0xFFFF0000u);  // bf16 dim 2*sub+1
    if (i & 1) { lo1 = fmaf(w, lo, lo1); hi1 = fmaf(w, hi, hi1); }
    else       { lo0 = fmaf(w, lo, lo0); hi0 = fmaf(w, hi, hi0); }
  }
}

__global__ __launch_bounds__(256, 4) void kgat_attn2(
    const int* __restrict__ item_idx, const int* __restrict__ adj,
    const float* __restrict__ item_tab,
    const uint32* __restrict__ ent32, const float* __restrict__ proj,
    const float* __restrict__ attn_W, const float* __restrict__ attn_b,
    float* __restrict__ naws, int B)
{
  const int lane = threadIdx.x & 63;
  const int wv   = threadIdx.x >> 6;
  const int b    = blockIdx.x * 4 + wv;
  if (b >= B) return;
  const int half = lane >> 5;
  const int sub  = lane & 31;

  const int* adjb = adj + (long)b * NN;

  // issue first two pair-groups before score math (overlap latency)
  uint32 GA[PGRP], GB[PGRP];
  load_pair_grp(GA, adjb, ent32, 0, half, sub);
  load_pair_grp(GB, adjb, ent32, 1, half, sub);

  const float item = item_tab[(long)item_idx[b] * D + lane];
  const float base = wave_sum64(item * attn_W[lane]) + attn_b[0];  // uniform

  // scores: lane n gathers proj[adj[n]] (800KB, L2-hot); fixed-max softmax
  const int myn = lane < NN ? lane : NN - 1;
  int mi = adjb[myn]; mi = mi < 0 ? 0 : mi;
  float s = proj[mi] + base;
  s = s > 0.f ? s : 0.2f * s;                     // leaky_relu(0.2)
  // scores are leaky_relu of ~unit-variance dots, bounded well below 8 ->
  // exp(s-8) can't overflow, denom can't underflow to 0.
  const float e = (lane < NN) ? __expf(s - 8.0f) : 0.f;
  const float denom = wave_sum64(e);

  // weighted sum over pairs, double-buffered (all indices compile-time)
  float lo0 = 0.f, lo1 = 0.f, hi0 = 0.f, hi1 = 0.f;
  acc_pair_grp(GA, e, 0, half, lo0, lo1, hi0, hi1);
  load_pair_grp(GA, adjb, ent32, 2, half, sub);
  acc_pair_grp(GB, e, 1, half, lo0, lo1, hi0, hi1);
  load_pair_grp(GB, adjb, ent32, 3, half, sub);
  acc_pair_grp(GA, e, 2, half, lo0, lo1, hi0, hi1);
  load_pair_grp(GA, adjb, ent32, 4, half, sub);
  acc_pair_grp(GB, e, 3, half, lo0, lo1, hi0, hi1);
  acc_pair_grp(GA, e, 4, half, lo0, lo1, hi0, hi1);

  // combine even/odd-neighbor halves: lane s and lane s+32 hold partial sums
  float nlo = lo0 + lo1;
  float nhi = hi0 + hi1;
  nlo += __shfl_xor(nlo, 32, 64);
  nhi += __shfl_xor(nhi, 32, 64);

  const float inv = 1.0f / denom;
  if (lane < 32) {                                 // coalesced float2 store
    float2 val = make_float2(nlo * inv, nhi * inv);
    *(float2*)(naws + (long)b * D + 2 * sub) = val;
  }
}

// ============ M: joint MLP, 4 elements/wave, LDS broadcast (R18-best) =======
__global__ __launch_bounds__(256, 4) void kgat_mlp4(
    const int* __restrict__ user_idx, const int* __restrict__ item_idx,
    const float* __restrict__ user_tab, const float* __restrict__ item_tab,
    const float* __restrict__ naws,
    const float* __restrict__ W1, const float* __restrict__ b1,
    const float* __restrict__ W2, const float* __restrict__ b2,
    const float* __restrict__ cW, const float* __restrict__ cb,
    const float* __restrict__ oW, const float* __restrict__ ob,
    float* __restrict__ out, int B)
{
  __shared__ __align__(16) float s_a[4 * 4 * D];   // activations (4 elem/wave)
  __shared__ __align__(16) float s_i[4 * 4 * D];   // items

  const int lane = threadIdx.x & 63;
  const int wv   = threadIdx.x >> 6;
  const int b0   = (blockIdx.x * 4 + wv) * 4;
  if (b0 >= B) return;

  float* saA = s_a + (wv * 4 + 0) * D;
  float* saB = s_a + (wv * 4 + 1) * D;
  float* saC = s_a + (wv * 4 + 2) * D;
  float* saD = s_a + (wv * 4 + 3) * D;
  float* siA = s_i + (wv * 4 + 0) * D;
  float* siB = s_i + (wv * 4 + 1) * D;
  float* siC = s_i + (wv * 4 + 2) * D;
  float* siD = s_i + (wv * 4 + 3) * D;

  const int bA = b0 + 0 < B ? b0 + 0 : B - 1;
  const int bB = b0 + 1 < B ? b0 + 1 : B - 1;
  const int bC = b0 + 2 < B ? b0 + 2 : B - 1;
  const int bD = b0 + 3 < B ? b0 + 3 : B - 1;

  // loads (coalesced 256B rows); na/item go straight to LDS, user persists
  saA[lane] = naws[(long)bA * D + lane];
  saB[lane] = naws[(long)bB * D + lane];
  saC[lane] = naws[(long)bC * D + lane];
  saD[lane] = naws[(long)bD * D + lane];
  siA[lane] = item_tab[(long)item_idx[bA] * D + lane];
  siB[lane] = item_tab[(long)item_idx[bB] * D + lane];
  siC[lane] = item_tab[(long)item_idx[bC] * D + lane];
  siD[lane] = item_tab[(long)item_idx[bD] * D + lane];
  const float usA = user_tab[(long)user_idx[bA] * D + lane];
  const float usB = user_tab[(long)user_idx[bB] * D + lane];
  const float usC = user_tab[(long)user_idx[bC] * D + lane];
  const float usD = user_tab[(long)user_idx[bD] * D + lane];

  // ---- h = relu(na @ W1 + b1): one weight column feeds all 4 elements ----
  const float b1v = b1[lane];
  float hA0 = b1v, hA1 = 0.f, hB0 = b1v, hB1 = 0.f;
  float hC0 = b1v, hC1 = 0.f, hD0 = b1v, hD1 = 0.f;
#pragma unroll
  for (int d = 0; d < D; d += 4) {
    const float w0 = W1[(d + 0) * D + lane];
    const float w1 = W1[(d + 1) * D + lane];
    const float w2 = W1[(d + 2) * D + lane];
    const float w3 = W1[(d + 3) * D + lane];
    const float4 cA = *(const float4*)(saA + d);
    const float4 cB = *(const float4*)(saB + d);
    const float4 cC = *(const float4*)(saC + d);
    const float4 cD = *(const float4*)(saD + d);
    hA0 = fmaf(cA.x, w0, hA0); hA1 = fmaf(cA.y, w1, hA1);
    hA0 = fmaf(cA.z, w2, hA0); hA1 = fmaf(cA.w, w3, hA1);
    hB0 = fmaf(cB.x, w0, hB0); hB1 = fmaf(cB.y, w1, hB1);
    hB0 = fmaf(cB.z, w2, hB0); hB1 = fmaf(cB.w, w3, hB1);
    hC0 = fmaf(cC.x, w0, hC0); hC1 = fmaf(cC.y, w1, hC1);
    hC0 = fmaf(cC.z, w2, hC0); hC1 = fmaf(cC.w, w3, hC1);
    hD0 = fmaf(cD.x, w0, hD0); hD1 = fmaf(cD.y, w1, hD1);
    hD0 = fmaf(cD.z, w2, hD0); hD1 = fmaf(cD.w, w3, hD1);
  }
  saA[lane] = fmaxf(hA0 + hA1, 0.f);
  saB[lane] = fmaxf(hB0 + hB1, 0.f);
  saC[lane] = fmaxf(hC0 + hC1, 0.f);
  saD[lane] = fmaxf(hD0 + hD1, 0.f);

  // ---- r = h @ W2 + b2 ----
  const float b2v = b2[lane];
  float rA0 = b2v, rA1 = 0.f, rB0 = b2v, rB1 = 0.f;
  float rC0 = b2v, rC1 = 0.f, rD0 = b2v, rD1 = 0.f;
#pragma unroll
  for (int d = 0; d < D; d += 4) {
    const float w0 = W2[(d + 0) * D + lane];
    const float w1 = W2[(d + 1) * D + lane];
    const float w2 = W2[(d + 2) * D + lane];
    const float w3 = W2[(d + 3) * D + lane];
    const float4 cA = *(const float4*)(saA + d);
    const float4 cB = *(const float4*)(saB + d);
    const float4 cC = *(const float4*)(saC + d);
    const float4 cD = *(const float4*)(saD + d);
    rA0 = fmaf(cA.x, w0, rA0); rA1 = fmaf(cA.y, w1, rA1);
    rA0 = fmaf(cA.z, w2, rA0); rA1 = fmaf(cA.w, w3, rA1);
    rB0 = fmaf(cB.x, w0, rB0); rB1 = fmaf(cB.y, w1, rB1);
    rB0 = fmaf(cB.z, w2, rB0); rB1 = fmaf(cB.w, w3, rB1);
    rC0 = fmaf(cC.x, w0, rC0); rC1 = fmaf(cC.y, w1, rC1);
    rC0 = fmaf(cC.z, w2, rC0); rC1 = fmaf(cC.w, w3, rC1);
    rD0 = fmaf(cD.x, w0, rD0); rD1 = fmaf(cD.y, w1, rD1);
    rD0 = fmaf(cD.z, w2, rD0); rD1 = fmaf(cD.w, w3, rD1);
  }
  saA[lane] = rA0 + rA1;
  saB[lane] = rB0 + rB1;
  saC[lane] = rC0 + rC1;
  saD[lane] = rD0 + rD1;

  // ---- f = relu([item, r] @ cW + cb) ----
  const float cbv = cb[lane];
  float fA0 = cbv, fA1 = 0.f, fB0 = cbv, fB1 = 0.f;
  float fC0 = cbv, fC1 = 0.f, fD0 = cbv, fD1 = 0.f;
#pragma unroll
  for (int k = 0; k < D; k += 4) {
    const float w0 = cW[(k + 0) * D + lane];
    const float w1 = cW[(k + 1) * D + lane];
    const float w2 = cW[(k + 2) * D + lane];
    const float w3 = cW[(k + 3) * D + lane];
    const float4 cA = *(const float4*)(siA + k);
    const float4 cB = *(const float4*)(siB + k);
    const float4 cC = *(const float4*)(siC + k);
    const float4 cD = *(const float4*)(siD + k);
    fA0 = fmaf(cA.x, w0, fA0); fA1 = fmaf(cA.y, w1, fA1);
    fA0 = fmaf(cA.z, w2, fA0); fA1 = fmaf(cA.w, w3, fA1);
    fB0 = fmaf(cB.x, w0, fB0); fB1 = fmaf(cB.y, w1, fB1);
    fB0 = fmaf(cB.z, w2, fB0); fB1 = fmaf(cB.w, w3, fB1);
    fC0 = fmaf(cC.x, w0, fC0); fC1 = fmaf(cC.y, w1, fC1);
    fC0 = fmaf(cC.z, w2, fC0); fC1 = fmaf(cC.w, w3, fC1);
    fD0 = fmaf(cD.x, w0, fD0); fD1 = fmaf(cD.y, w1, fD1);
    fD0 = fmaf(cD.z, w2, fD0); fD1 = fmaf(cD.w, w3, fD1);
  }
#pragma unroll
  for (int k = 0; k < D; k += 4) {
    const float w0 = cW[(D + k + 0) * D + lane];
    const float w1 = cW[(D + k + 1) * D + lane];
    const float w2 = cW[(D + k + 2) * D + lane];
    const float w3 = cW[(D + k + 3) * D + lane];
    const float4 cA = *(const float4*)(saA + k);
    const float4 cB = *(const float4*)(saB + k);
    const float4 cC = *(const float4*)(saC + k);
    const float4 cD = *(const float4*)(saD + k);
    fA0 = fmaf(cA.x, w0, fA0); fA1 = fmaf(cA.y, w1, fA1);
    fA0 = fmaf(cA.z, w2, fA0); fA1 = fmaf(cA.w, w3, fA1);
    fB0 = fmaf(cB.x, w0, fB0); fB1 = fmaf(cB.y, w1, fB1);
    fB0 = fmaf(cB.z, w2, fB0); fB1 = fmaf(cB.w, w3, fB1);
    fC0 = fmaf(cC.x, w0, fC0); fC1 = fmaf(cC.y, w1, fC1);
    fC0 = fmaf(cC.z, w2, fC0); fC1 = fmaf(cC.w, w3, fC1);
    fD0 = fmaf(cD.x, w0, fD0); fD1 = fmaf(cD.y, w1, fD1);
    fD0 = fmaf(cD.z, w2, fD0); fD1 = fmaf(cD.w, w3, fD1);
  }
  const float fA = fmaxf(fA0 + fA1, 0.f);
  const float fB = fmaxf(fB0 + fB1, 0.f);
  const float fC = fmaxf(fC0 + fC1, 0.f);
  const float fD = fmaxf(fD0 + fD1, 0.f);

  // ---- score = dot([user, f], oW) + ob ----
  const float oWu = oW[lane];
  const float oWf = oW[D + lane];
  const float ob0 = ob[0];
  const float scA = wave_sum64(fmaf(usA, oWu, fA * oWf));
  const float scB = wave_sum64(fmaf(usB, oWu, fB * oWf));
  const float scC = wave_sum64(fmaf(usC, oWu, fC * oWf));
  const float scD = wave_sum64(fmaf(usD, oWu, fD * oWf));
  if (lane == 0) {
    out[bA] = scA + ob0;
    if (bB != bA) out[bB] = scB + ob0;
    if (bC != bB) out[bC] = scC + ob0;
    if (bD != bC) out[bD] = scD + ob0;
  }
}

// ================= fallback: exact R3 kernel (small/no workspace) ===========
__device__ __forceinline__ void load_grp(float (&buf)[GRP],
                                         const int* __restrict__ adjb,
                                         const float* __restrict__ ent_tab,
                                         int g, int lane) {
#pragma unroll
  for (int i = 0; i < GRP; ++i) {
    int t = adjb[g * GRP + i];
    t = t < 0 ? 0 : t;
    buf[i] = ent_tab[(long)t * D + lane];
  }
}

__device__ __forceinline__ void proc_grp(const float (&buf)[GRP],
                                         float Wn, float base,
                                         float& l0, float& l1, float& na) {
  float ex[GRP];
#pragma unroll
  for (int i = 0; i < GRP; ++i) {
    float t = wave_sum64(buf[i] * Wn) + base;
    t = t > 0.f ? t : 0.2f * t;
    ex[i] = __expf(t - 8.0f);
  }
#pragma unroll
  for (int i = 0; i < GRP; ++i) {
    if (i & 1) l1 += ex[i]; else l0 += ex[i];
    na = fmaf(ex[i], buf[i], na);
  }
}

__global__ __launch_bounds__(256, 4) void kgat_r3(
    const int* __restrict__ user_idx, const int* __restrict__ item_idx,
    const int* __restrict__ adj,
    const float* __restrict__ user_tab, const float* __restrict__ item_tab,
    const float* __restrict__ ent_tab,
    const float* __restrict__ attn_W, const float* __restrict__ attn_b,
    const float* __restrict__ W1, const float* __restrict__ b1,
    const float* __restrict__ W2, const float* __restrict__ b2,
    const float* __restrict__ cW, const float* __restrict__ cb,
    const float* __restrict__ oW, const float* __restrict__ ob,
    float* __restrict__ out, int B)
{
  const int lane = threadIdx.x & 63;
  const int wv   = threadIdx.x >> 6;
  const int b    = blockIdx.x * 4 + wv;
  if (b >= B) return;

  const float user = user_tab[(long)user_idx[b] * D + lane];
  const float oWu  = oW[lane];
  const float oWf  = oW[D + lane];
  const float item = item_tab[(long)item_idx[b] * D + lane];
  const float Wi   = attn_W[lane];
  const float Wn   = attn_W[D + lane];
  const float base = wave_sum64(item * Wi) + attn_b[0];
  const int* adjb = adj + b * NN;

  float na = 0.f, l0 = 0.f, l1 = 0.f;
  float A[GRP], Bv[GRP];
  load_grp(A,  adjb, ent_tab, 0, lane);
  load_grp(Bv, adjb, ent_tab, 1, lane);
  proc_grp(A,  Wn, base, l0, l1, na);
  load_grp(A,  adjb, ent_tab, 2, lane);
  proc_grp(Bv, Wn, base, l0, l1, na);
  load_grp(Bv, adjb, ent_tab, 3, lane);
  proc_grp(A,  Wn, base, l0, l1, na);
  load_grp(A,  adjb, ent_tab, 4, lane);
  proc_grp(Bv, Wn, base, l0, l1, na);
  proc_grp(A,  Wn, base, l0, l1, na);
  na /= (l0 + l1);

  float h0 = b1[lane], h1 = 0.f, h2 = 0.f, h3 = 0.f;
#pragma unroll
  for (int d = 0; d < D; d += 4) {
    h0 = fmaf(readlane_f(na, d + 0), W1[(d + 0) * D + lane], h0);
    h1 = fmaf(readlane_f(na, d + 1), W1[(d + 1) * D + lane], h1);
    h2 = fmaf(readlane_f(na, d + 2), W1[(d + 2) * D + lane], h2);
    h3 = fmaf(readlane_f(na, d + 3), W1[(d + 3) * D + lane], h3);
  }
  const float h = fmaxf((h0 + h1) + (h2 + h3), 0.f);

  float r0 = b2[lane], r1 = 0.f, r2 = 0.f, r3 = 0.f;
#pragma unroll
  for (int d = 0; d < D; d += 4) {
    r0 = fmaf(readlane_f(h, d + 0), W2[(d + 0) * D + lane], r0);
    r1 = fmaf(readlane_f(h, d + 1), W2[(d + 1) * D + lane], r1);
    r2 = fmaf(readlane_f(h, d + 2), W2[(d + 2) * D + lane], r2);
    r3 = fmaf(readlane_f(h, d + 3), W2[(d + 3) * D + lane], r3);
  }
  const float r = (r0 + r1) + (r2 + r3);

  float f0 = cb[lane], f1 = 0.f, f2 = 0.f, f3 = 0.f;
#pragma unroll
  for (int k = 0; k < D; k += 4) {
    f0 = fmaf(readlane_f(item, k + 0), cW[(k + 0) * D + lane], f0);
    f1 = fmaf(readlane_f(item, k + 1), cW[(k + 1) * D + lane], f1);
    f2 = fmaf(readlane_f(item, k + 2), cW[(k + 2) * D + lane], f2);
    f3 = fmaf(readlane_f(item, k + 3), cW[(k + 3) * D + lane], f3);
  }
#pragma unroll
  for (int k = 0; k < D; k += 4) {
    f0 = fmaf(readlane_f(r, k + 0), cW[(D + k + 0) * D + lane], f0);
    f1 = fmaf(readlane_f(r, k + 1), cW[(D + k + 1) * D + lane], f1);
    f2 = fmaf(readlane_f(r, k + 2), cW[(D + k + 2) * D + lane], f2);
    f3 = fmaf(readlane_f(r, k + 3), cW[(D + k + 3) * D + lane], f3);
  }
  const float f = fmaxf((f0 + f1) + (f2 + f3), 0.f);

  const float sc = wave_sum64(fmaf(user, oWu, f * oWf));
  if (lane == 0) out[b] = sc + ob[0];
}

extern "C" void kernel_launch(void* const* d_in, const int* in_sizes, int n_in,
                              void* d_out, int out_size, void* d_ws, size_t ws_size,
                              hipStream_t stream) {
  const int*   user_idx = (const int*)d_in[0];
  const int*   item_idx = (const int*)d_in[1];
  const int*   adj      = (const int*)d_in[2];
  const float* user_tab = (const float*)d_in[3];
  const float* item_tab = (const float*)d_in[4];
  const float* ent_tab  = (const float*)d_in[5];
  const float* attn_W   = (const float*)d_in[6];
  const float* attn_b   = (const float*)d_in[7];
  const float* W1       = (const float*)d_in[8];
  const float* b1       = (const float*)d_in[9];
  const float* W2       = (const float*)d_in[10];
  const float* b2       = (const float*)d_in[11];
  const float* cW       = (const float*)d_in[12];
  const float* cb       = (const float*)d_in[13];
  const float* oW       = (const float*)d_in[14];
  const float* ob       = (const float*)d_in[15];
  float* out = (float*)d_out;

  const int B    = in_sizes[0];
  const int rows = in_sizes[5] / D;               // entity count

  // ws layout: [proj f32][ent_bf bf16][naws f32], 256B-aligned sections
  const size_t off_bf = ((size_t)rows * 4 + 255) & ~(size_t)255;
  const size_t off_na = (off_bf + (size_t)rows * D * 2 + 255) & ~(size_t)255;
  const size_t need   = off_na + (size_t)B * D * 4;

  if (ws_size >= need) {
    float*    proj   = (float*)d_ws;
    ushort16* ent_bf = (ushort16*)((char*)d_ws + off_bf);
    float*    naws   = (float*)((char*)d_ws + off_na);
    const int waves   = (rows + GRP - 1) / GRP;
    const int pblocks = (waves + 3) / 4;
    const int ablocks = (B + 3) / 4;              // attention: 1 elem/wave
    const int mblocks = (B + 15) / 16;            // MLP: 4 elems/wave
    ent_proj<<<pblocks, 256, 0, stream>>>(ent_tab, attn_W, proj, ent_bf, rows);
    kgat_attn2<<<ablocks, 256, 0, stream>>>(item_idx, adj, item_tab,
                                            (const uint32*)ent_bf, proj,
                                            attn_W, attn_b, naws, B);
    kgat_mlp4<<<mblocks, 256, 0, stream>>>(user_idx, item_idx, user_tab,
                                           item_tab, naws, W1, b1, W2, b2,
                                           cW, cb, oW, ob, out, B);
  } else {
    const int blocks = (B + 3) / 4;
    kgat_r3<<<blocks, 256, 0, stream>>>(user_idx, item_idx, adj,
                                        user_tab, item_tab, ent_tab,
                                        attn_W, attn_b, W1, b1, W2, b2,
                                        cW, cb, oW, ob, out, B);
  }
}

// Round 21
// 52.127 us; speedup vs baseline: 1.2804x; 1.1057x over previous
//
#include <hip/hip_runtime.h>

#define NN 50
#define D 64
#define GRP 10

typedef unsigned int uint32;
typedef unsigned short ushort16;

__device__ __forceinline__ float wave_sum64(float x) {
#pragma unroll
  for (int off = 32; off > 0; off >>= 1)
    x += __shfl_xor(x, off, 64);
  return x;
}

__device__ __forceinline__ float readlane_f(float v, int l) {
  return __uint_as_float(__builtin_amdgcn_readlane(__float_as_uint(v), l));
}

__device__ __forceinline__ ushort16 f32_to_bf16(float f) {
  uint32 u = __float_as_uint(f);
  u += 0x7FFF + ((u >> 16) & 1);          // round-to-nearest-even
  return (ushort16)(u >> 16);
}

// ==== PREP: blocks [0,pblocks) = ent_proj; blocks [pblocks,+16) = W2@cW fuse =
// proj[e] = dot(ent[e], Wn); ent_bf = bf16(ent);
// W2cW[d][j] = sum_k W2[d][k]*cW[(D+k)][j]; cb2[j] = cb[j] + sum_k b2[k]*cW[(D+k)][j]
__global__ __launch_bounds__(256, 4) void kgat_prep(
    const float* __restrict__ ent_tab, const float* __restrict__ attn_W,
    float* __restrict__ proj, ushort16* __restrict__ ent_bf, int rows,
    int pblocks,
    const float* __restrict__ W2, const float* __restrict__ b2,
    const float* __restrict__ cW, const float* __restrict__ cb,
    float* __restrict__ W2cW, float* __restrict__ cb2)
{
  const int lane = threadIdx.x & 63;
  const int wv   = threadIdx.x >> 6;

  if ((int)blockIdx.x < pblocks) {
    // ---------------- ent_proj (R10-proven) ----------------
    const long wave = (long)blockIdx.x * 4 + wv;
    const long base = wave * GRP;
    if (base >= rows) return;
    const float Wn = attn_W[D + lane];
    float v[GRP];
#pragma unroll
    for (int i = 0; i < GRP; ++i) {
      long r = base + i; if (r > rows - 1) r = rows - 1;
      v[i] = ent_tab[r * D + lane];         // coalesced, contiguous rows
    }
    float s[GRP];
#pragma unroll
    for (int i = 0; i < GRP; ++i)
      s[i] = wave_sum64(v[i] * Wn);         // 10 independent butterfly chains
#pragma unroll
    for (int i = 0; i < GRP; ++i) {
      const long r = base + i;
      if (r < rows) ent_bf[r * D + lane] = f32_to_bf16(v[i]);
    }
    if (lane == 0) {
#pragma unroll
      for (int i = 0; i < GRP; ++i)
        if (base + i < rows) proj[base + i] = s[i];
    }
  } else {
    // ---------------- weight fusion: 16 blocks x 4 waves = 64 rows d ------
    const int d = ((int)blockIdx.x - pblocks) * 4 + wv;   // 0..63
    float acc = 0.f;
#pragma unroll 8
    for (int k = 0; k < D; ++k)
      acc = fmaf(W2[d * D + k], cW[(D + k) * D + lane], acc);
    W2cW[d * D + lane] = acc;
    if (d == 0) {
      float a2 = 0.f;
#pragma unroll 8
      for (int k = 0; k < D; ++k)
        a2 = fmaf(b2[k], cW[(D + k) * D + lane], a2);
      cb2[lane] = cb[lane] + a2;
    }
  }
}

// ===== A: attention, paired-row gathers (R20-proven, 2 rows / wave-load) ====
#define PGRP 5

__device__ __forceinline__ void load_pair_grp(uint32 (&buf)[PGRP],
                                              const int* __restrict__ adjb,
                                              const uint32* __restrict__ ent32,
                                              int g, int half, int sub) {
#pragma unroll
  for (int i = 0; i < PGRP; ++i) {
    const int p = g * PGRP + i;
    int t0 = adjb[2 * p + 0]; t0 = t0 < 0 ? 0 : t0;
    int t1 = adjb[2 * p + 1]; t1 = t1 < 0 ? 0 : t1;
    const int t = half ? t1 : t0;
    buf[i] = ent32[(size_t)t * 32 + sub];   // 4B/lane, 2 rows per instruction
  }
}

__device__ __forceinline__ void acc_pair_grp(const uint32 (&buf)[PGRP],
                                             float e, int g, int half,
                                             float& lo0, float& lo1,
                                             float& hi0, float& hi1) {
#pragma unroll
  for (int i = 0; i < PGRP; ++i) {
    const int p = g * PGRP + i;
    const float w0 = readlane_f(e, 2 * p + 0);
    const float w1 = readlane_f(e, 2 * p + 1);
    const float w  = half ? w1 : w0;
    const float lo = __uint_as_float(buf[i] << 16);          // bf16 dim 2*sub
    const float hi = __uint_as_float(buf[i] & 0xFFFF0000u);  // bf16 dim 2*sub+1
    if (i & 1) { lo1 = fmaf(w, lo, lo1); hi1 = fmaf(w, hi, hi1); }
    else       { lo0 = fmaf(w, lo, lo0); hi0 = fmaf(w, hi, hi0); }
  }
}

__global__ __launch_bounds__(256, 4) void kgat_attn2(
    const int* __restrict__ item_idx, const int* __restrict__ adj,
    const float* __restrict__ item_tab,
    const uint32* __restrict__ ent32, const float* __restrict__ proj,
    const float* __restrict__ attn_W, const float* __restrict__ attn_b,
    float* __restrict__ naws, int B)
{
  const int lane = threadIdx.x & 63;
  const int wv   = threadIdx.x >> 6;
  const int b    = blockIdx.x * 4 + wv;
  if (b >= B) return;
  const int half = lane >> 5;
  const int sub  = lane & 31;

  const int* adjb = adj + (long)b * NN;

  uint32 GA[PGRP], GB[PGRP];
  load_pair_grp(GA, adjb, ent32, 0, half, sub);
  load_pair_grp(GB, adjb, ent32, 1, half, sub);

  const float item = item_tab[(long)item_idx[b] * D + lane];
  const float base = wave_sum64(item * attn_W[lane]) + attn_b[0];  // uniform

  const int myn = lane < NN ? lane : NN - 1;
  int mi = adjb[myn]; mi = mi < 0 ? 0 : mi;
  float s = proj[mi] + base;
  s = s > 0.f ? s : 0.2f * s;                     // leaky_relu(0.2)
  // scores are leaky_relu of ~unit-variance dots, bounded well below 8 ->
  // exp(s-8) can't overflow, denom can't underflow to 0.
  const float e = (lane < NN) ? __expf(s - 8.0f) : 0.f;
  const float denom = wave_sum64(e);

  float lo0 = 0.f, lo1 = 0.f, hi0 = 0.f, hi1 = 0.f;
  acc_pair_grp(GA, e, 0, half, lo0, lo1, hi0, hi1);
  load_pair_grp(GA, adjb, ent32, 2, half, sub);
  acc_pair_grp(GB, e, 1, half, lo0, lo1, hi0, hi1);
  load_pair_grp(GB, adjb, ent32, 3, half, sub);
  acc_pair_grp(GA, e, 2, half, lo0, lo1, hi0, hi1);
  load_pair_grp(GA, adjb, ent32, 4, half, sub);
  acc_pair_grp(GB, e, 3, half, lo0, lo1, hi0, hi1);
  acc_pair_grp(GA, e, 4, half, lo0, lo1, hi0, hi1);

  float nlo = lo0 + lo1;
  float nhi = hi0 + hi1;
  nlo += __shfl_xor(nlo, 32, 64);
  nhi += __shfl_xor(nhi, 32, 64);

  const float inv = 1.0f / denom;
  if (lane < 32) {                                 // coalesced float2 store
    float2 val = make_float2(nlo * inv, nhi * inv);
    *(float2*)(naws + (long)b * D + 2 * sub) = val;
  }
}

// ===== M: fused MLP, 4 elems/wave; na/item via scalar loads, h via LDS ======
// f = relu( item@cW_top + h@W2cW + cb2 ), h = relu(na@W1 + b1)
__global__ __launch_bounds__(256, 4) void kgat_mlpf(
    const int* __restrict__ user_idx, const int* __restrict__ item_idx,
    const float* __restrict__ user_tab, const float* __restrict__ item_tab,
    const float* __restrict__ naws,
    const float* __restrict__ W1, const float* __restrict__ b1,
    const float* __restrict__ cW,
    const float* __restrict__ W2cW, const float* __restrict__ cb2,
    const float* __restrict__ oW, const float* __restrict__ ob,
    float* __restrict__ out, int B)
{
  __shared__ __align__(16) float s_h[4 * 4 * D];   // h broadcast (4 elem/wave)

  const int lane = threadIdx.x & 63;
  const int wv   = threadIdx.x >> 6;
  const int b0   = (blockIdx.x * 4 + wv) * 4;
  if (b0 >= B) return;

  float* shA = s_h + (wv * 4 + 0) * D;
  float* shB = s_h + (wv * 4 + 1) * D;
  float* shC = s_h + (wv * 4 + 2) * D;
  float* shD = s_h + (wv * 4 + 3) * D;

  const int bA = b0 + 0 < B ? b0 + 0 : B - 1;
  const int bB = b0 + 1 < B ? b0 + 1 : B - 1;
  const int bC = b0 + 2 < B ? b0 + 2 : B - 1;
  const int bD = b0 + 3 < B ? b0 + 3 : B - 1;

  // wave-uniform activation bases -> scalar-pipe loads (s_load_dwordx4)
  const int uA = __builtin_amdgcn_readfirstlane(bA);
  const int uB = __builtin_amdgcn_readfirstlane(bB);
  const int uC = __builtin_amdgcn_readfirstlane(bC);
  const int uD = __builtin_amdgcn_readfirstlane(bD);
  const float* napA = naws + (long)uA * D;
  const float* napB = naws + (long)uB * D;
  const float* napC = naws + (long)uC * D;
  const float* napD = naws + (long)uD * D;
  const int iiA = __builtin_amdgcn_readfirstlane(item_idx[bA]);
  const int iiB = __builtin_amdgcn_readfirstlane(item_idx[bB]);
  const int iiC = __builtin_amdgcn_readfirstlane(item_idx[bC]);
  const int iiD = __builtin_amdgcn_readfirstlane(item_idx[bD]);
  const float* itpA = item_tab + (long)iiA * D;
  const float* itpB = item_tab + (long)iiB * D;
  const float* itpC = item_tab + (long)iiC * D;
  const float* itpD = item_tab + (long)iiD * D;

  // user rows per-lane (lane = dim), coalesced
  const float usA = user_tab[(long)user_idx[bA] * D + lane];
  const float usB = user_tab[(long)user_idx[bB] * D + lane];
  const float usC = user_tab[(long)user_idx[bC] * D + lane];
  const float usD = user_tab[(long)user_idx[bD] * D + lane];

  // ---- phase 1: h = relu(na @ W1 + b1); na via uniform float4 chunks ----
  const float b1v = b1[lane];
  float hA0 = b1v, hA1 = 0.f, hB0 = b1v, hB1 = 0.f;
  float hC0 = b1v, hC1 = 0.f, hD0 = b1v, hD1 = 0.f;
#pragma unroll
  for (int d = 0; d < D; d += 4) {
    const float w0 = W1[(d + 0) * D + lane];
    const float w1 = W1[(d + 1) * D + lane];
    const float w2 = W1[(d + 2) * D + lane];
    const float w3 = W1[(d + 3) * D + lane];
    const float4 aA = *(const float4*)(napA + d);
    const float4 aB = *(const float4*)(napB + d);
    const float4 aC = *(const float4*)(napC + d);
    const float4 aD = *(const float4*)(napD + d);
    hA0 = fmaf(aA.x, w0, hA0); hA1 = fmaf(aA.y, w1, hA1);
    hA0 = fmaf(aA.z, w2, hA0); hA1 = fmaf(aA.w, w3, hA1);
    hB0 = fmaf(aB.x, w0, hB0); hB1 = fmaf(aB.y, w1, hB1);
    hB0 = fmaf(aB.z, w2, hB0); hB1 = fmaf(aB.w, w3, hB1);
    hC0 = fmaf(aC.x, w0, hC0); hC1 = fmaf(aC.y, w1, hC1);
    hC0 = fmaf(aC.z, w2, hC0); hC1 = fmaf(aC.w, w3, hC1);
    hD0 = fmaf(aD.x, w0, hD0); hD1 = fmaf(aD.y, w1, hD1);
    hD0 = fmaf(aD.z, w2, hD0); hD1 = fmaf(aD.w, w3, hD1);
  }
  shA[lane] = fmaxf(hA0 + hA1, 0.f);               // wave-private, no barrier
  shB[lane] = fmaxf(hB0 + hB1, 0.f);
  shC[lane] = fmaxf(hC0 + hC1, 0.f);
  shD[lane] = fmaxf(hD0 + hD1, 0.f);

  // ---- phase 2: f = relu(item@cW_top + h@W2cW + cb2) ----
  const float cb2v = cb2[lane];
  float fA0 = cb2v, fA1 = 0.f, fB0 = cb2v, fB1 = 0.f;
  float fC0 = cb2v, fC1 = 0.f, fD0 = cb2v, fD1 = 0.f;
#pragma unroll
  for (int d = 0; d < D; d += 4) {                 // item side (scalar chunks)
    const float w0 = cW[(d + 0) * D + lane];
    const float w1 = cW[(d + 1) * D + lane];
    const float w2 = cW[(d + 2) * D + lane];
    const float w3 = cW[(d + 3) * D + lane];
    const float4 aA = *(const float4*)(itpA + d);
    const float4 aB = *(const float4*)(itpB + d);
    const float4 aC = *(const float4*)(itpC + d);
    const float4 aD = *(const float4*)(itpD + d);
    fA0 = fmaf(aA.x, w0, fA0); fA1 = fmaf(aA.y, w1, fA1);
    fA0 = fmaf(aA.z, w2, fA0); fA1 = fmaf(aA.w, w3, fA1);
    fB0 = fmaf(aB.x, w0, fB0); fB1 = fmaf(aB.y, w1, fB1);
    fB0 = fmaf(aB.z, w2, fB0); fB1 = fmaf(aB.w, w3, fB1);
    fC0 = fmaf(aC.x, w0, fC0); fC1 = fmaf(aC.y, w1, fC1);
    fC0 = fmaf(aC.z, w2, fC0); fC1 = fmaf(aC.w, w3, fC1);
    fD0 = fmaf(aD.x, w0, fD0); fD1 = fmaf(aD.y, w1, fD1);
    fD0 = fmaf(aD.z, w2, fD0); fD1 = fmaf(aD.w, w3, fD1);
  }
#pragma unroll
  for (int d = 0; d < D; d += 4) {                 // h side (LDS broadcast)
    const float w0 = W2cW[(d + 0) * D + lane];
    const float w1 = W2cW[(d + 1) * D + lane];
    const float w2 = W2cW[(d + 2) * D + lane];
    const float w3 = W2cW[(d + 3) * D + lane];
    const float4 cA = *(const float4*)(shA + d);
    const float4 cB = *(const float4*)(shB + d);
    const float4 cC = *(const float4*)(shC + d);
    const float4 cD = *(const float4*)(shD + d);
    fA0 = fmaf(cA.x, w0, fA0); fA1 = fmaf(cA.y, w1, fA1);
    fA0 = fmaf(cA.z, w2, fA0); fA1 = fmaf(cA.w, w3, fA1);
    fB0 = fmaf(cB.x, w0, fB0); fB1 = fmaf(cB.y, w1, fB1);
    fB0 = fmaf(cB.z, w2, fB0); fB1 = fmaf(cB.w, w3, fB1);
    fC0 = fmaf(cC.x, w0, fC0); fC1 = fmaf(cC.y, w1, fC1);
    fC0 = fmaf(cC.z, w2, fC0); fC1 = fmaf(cC.w, w3, fC1);
    fD0 = fmaf(cD.x, w0, fD0); fD1 = fmaf(cD.y, w1, fD1);
    fD0 = fmaf(cD.z, w2, fD0); fD1 = fmaf(cD.w, w3, fD1);
  }
  const float fA = fmaxf(fA0 + fA1, 0.f);
  const float fB = fmaxf(fB0 + fB1, 0.f);
  const float fC = fmaxf(fC0 + fC1, 0.f);
  const float fD = fmaxf(fD0 + fD1, 0.f);

  // ---- score = dot([user, f], oW) + ob ----
  const float oWu = oW[lane];
  const float oWf = oW[D + lane];
  const float ob0 = ob[0];
  const float scA = wave_sum64(fmaf(usA, oWu, fA * oWf));
  const float scB = wave_sum64(fmaf(usB, oWu, fB * oWf));
  const float scC = wave_sum64(fmaf(usC, oWu, fC * oWf));
  const float scD = wave_sum64(fmaf(usD, oWu, fD * oWf));
  if (lane == 0) {
    out[bA] = scA + ob0;
    if (bB != bA) out[bB] = scB + ob0;
    if (bC != bB) out[bC] = scC + ob0;
    if (bD != bC) out[bD] = scD + ob0;
  }
}

// ================= fallback: exact R3 kernel (small/no workspace) ===========
__device__ __forceinline__ void load_grp(float (&buf)[GRP],
                                         const int* __restrict__ adjb,
                                         const float* __restrict__ ent_tab,
                                         int g, int lane) {
#pragma unroll
  for (int i = 0; i < GRP; ++i) {
    int t = adjb[g * GRP + i];
    t = t < 0 ? 0 : t;
    buf[i] = ent_tab[(long)t * D + lane];
  }
}

__device__ __forceinline__ void proc_grp(const float (&buf)[GRP],
                                         float Wn, float base,
                                         float& l0, float& l1, float& na) {
  float ex[GRP];
#pragma unroll
  for (int i = 0; i < GRP; ++i) {
    float t = wave_sum64(buf[i] * Wn) + base;
    t = t > 0.f ? t : 0.2f * t;
    ex[i] = __expf(t - 8.0f);
  }
#pragma unroll
  for (int i = 0; i < GRP; ++i) {
    if (i & 1) l1 += ex[i]; else l0 += ex[i];
    na = fmaf(ex[i], buf[i], na);
  }
}

__global__ __launch_bounds__(256, 4) void kgat_r3(
    const int* __restrict__ user_idx, const int* __restrict__ item_idx,
    const int* __restrict__ adj,
    const float* __restrict__ user_tab, const float* __restrict__ item_tab,
    const float* __restrict__ ent_tab,
    const float* __restrict__ attn_W, const float* __restrict__ attn_b,
    const float* __restrict__ W1, const float* __restrict__ b1,
    const float* __restrict__ W2, const float* __restrict__ b2,
    const float* __restrict__ cW, const float* __restrict__ cb,
    const float* __restrict__ oW, const float* __restrict__ ob,
    float* __restrict__ out, int B)
{
  const int lane = threadIdx.x & 63;
  const int wv   = threadIdx.x >> 6;
  const int b    = blockIdx.x * 4 + wv;
  if (b >= B) return;

  const float user = user_tab[(long)user_idx[b] * D + lane];
  const float oWu  = oW[lane];
  const float oWf  = oW[D + lane];
  const float item = item_tab[(long)item_idx[b] * D + lane];
  const float Wi   = attn_W[lane];
  const float Wn   = attn_W[D + lane];
  const float base = wave_sum64(item * Wi) + attn_b[0];
  const int* adjb = adj + b * NN;

  float na = 0.f, l0 = 0.f, l1 = 0.f;
  float A[GRP], Bv[GRP];
  load_grp(A,  adjb, ent_tab, 0, lane);
  load_grp(Bv, adjb, ent_tab, 1, lane);
  proc_grp(A,  Wn, base, l0, l1, na);
  load_grp(A,  adjb, ent_tab, 2, lane);
  proc_grp(Bv, Wn, base, l0, l1, na);
  load_grp(Bv, adjb, ent_tab, 3, lane);
  proc_grp(A,  Wn, base, l0, l1, na);
  load_grp(A,  adjb, ent_tab, 4, lane);
  proc_grp(Bv, Wn, base, l0, l1, na);
  proc_grp(A,  Wn, base, l0, l1, na);
  na /= (l0 + l1);

  float h0 = b1[lane], h1 = 0.f, h2 = 0.f, h3 = 0.f;
#pragma unroll
  for (int d = 0; d < D; d += 4) {
    h0 = fmaf(readlane_f(na, d + 0), W1[(d + 0) * D + lane], h0);
    h1 = fmaf(readlane_f(na, d + 1), W1[(d + 1) * D + lane], h1);
    h2 = fmaf(readlane_f(na, d + 2), W1[(d + 2) * D + lane], h2);
    h3 = fmaf(readlane_f(na, d + 3), W1[(d + 3) * D + lane], h3);
  }
  const float h = fmaxf((h0 + h1) + (h2 + h3), 0.f);

  float r0 = b2[lane], r1 = 0.f, r2 = 0.f, r3 = 0.f;
#pragma unroll
  for (int d = 0; d < D; d += 4) {
    r0 = fmaf(readlane_f(h, d + 0), W2[(d + 0) * D + lane], r0);
    r1 = fmaf(readlane_f(h, d + 1), W2[(d + 1) * D + lane], r1);
    r2 = fmaf(readlane_f(h, d + 2), W2[(d + 2) * D + lane], r2);
    r3 = fmaf(readlane_f(h, d + 3), W2[(d + 3) * D + lane], r3);
  }
  const float r = (r0 + r1) + (r2 + r3);

  float f0 = cb[lane], f1 = 0.f, f2 = 0.f, f3 = 0.f;
#pragma unroll
  for (int k = 0; k < D; k += 4) {
    f0 = fmaf(readlane_f(item, k + 0), cW[(k + 0) * D + lane], f0);
    f1 = fmaf(readlane_f(item, k + 1), cW[(k + 1) * D + lane], f1);
    f2 = fmaf(readlane_f(item, k + 2), cW[(k + 2) * D + lane], f2);
    f3 = fmaf(readlane_f(item, k + 3), cW[(k + 3) * D + lane], f3);
  }
#pragma unroll
  for (int k = 0; k < D; k += 4) {
    f0 = fmaf(readlane_f(r, k + 0), cW[(D + k + 0) * D + lane], f0);
    f1 = fmaf(readlane_f(r, k + 1), cW[(D + k + 1) * D + lane], f1);
    f2 = fmaf(readlane_f(r, k + 2), cW[(D + k + 2) * D + lane], f2);
    f3 = fmaf(readlane_f(r, k + 3), cW[(D + k + 3) * D + lane], f3);
  }
  const float f = fmaxf((f0 + f1) + (f2 + f3), 0.f);

  const float sc = wave_sum64(fmaf(user, oWu, f * oWf));
  if (lane == 0) out[b] = sc + ob[0];
}

extern "C" void kernel_launch(void* const* d_in, const int* in_sizes, int n_in,
                              void* d_out, int out_size, void* d_ws, size_t ws_size,
                              hipStream_t stream) {
  const int*   user_idx = (const int*)d_in[0];
  const int*   item_idx = (const int*)d_in[1];
  const int*   adj      = (const int*)d_in[2];
  const float* user_tab = (const float*)d_in[3];
  const float* item_tab = (const float*)d_in[4];
  const float* ent_tab  = (const float*)d_in[5];
  const float* attn_W   = (const float*)d_in[6];
  const float* attn_b   = (const float*)d_in[7];
  const float* W1       = (const float*)d_in[8];
  const float* b1       = (const float*)d_in[9];
  const float* W2       = (const float*)d_in[10];
  const float* b2       = (const float*)d_in[11];
  const float* cW       = (const float*)d_in[12];
  const float* cb       = (const float*)d_in[13];
  const float* oW       = (const float*)d_in[14];
  const float* ob       = (const float*)d_in[15];
  float* out = (float*)d_out;

  const int B    = in_sizes[0];
  const int rows = in_sizes[5] / D;               // entity count

  // ws layout: [proj f32][ent_bf bf16][naws f32][W2cW f32][cb2 f32]
  const size_t off_bf = ((size_t)rows * 4 + 255) & ~(size_t)255;
  const size_t off_na = (off_bf + (size_t)rows * D * 2 + 255) & ~(size_t)255;
  const size_t off_w2 = (off_na + (size_t)B * D * 4 + 255) & ~(size_t)255;
  const size_t off_cb = off_w2 + (size_t)D * D * 4;
  const size_t need   = off_cb + (size_t)D * 4;

  if (ws_size >= need) {
    float*    proj   = (float*)d_ws;
    ushort16* ent_bf = (ushort16*)((char*)d_ws + off_bf);
    float*    naws   = (float*)((char*)d_ws + off_na);
    float*    W2cW   = (float*)((char*)d_ws + off_w2);
    float*    cb2    = (float*)((char*)d_ws + off_cb);
    const int waves   = (rows + GRP - 1) / GRP;
    const int pblocks = (waves + 3) / 4;
    const int ablocks = (B + 3) / 4;              // attention: 1 elem/wave
    const int mblocks = (B + 15) / 16;            // MLP: 4 elems/wave
    kgat_prep<<<pblocks + 16, 256, 0, stream>>>(ent_tab, attn_W, proj, ent_bf,
                                                rows, pblocks, W2, b2, cW, cb,
                                                W2cW, cb2);
    kgat_attn2<<<ablocks, 256, 0, stream>>>(item_idx, adj, item_tab,
                                            (const uint32*)ent_bf, proj,
                                            attn_W, attn_b, naws, B);
    kgat_mlpf<<<mblocks, 256, 0, stream>>>(user_idx, item_idx, user_tab,
                                           item_tab, naws, W1, b1, cW,
                                           W2cW, cb2, oW, ob, out, B);
  } else {
    const int blocks = (B + 3) / 4;
    kgat_r3<<<blocks, 256, 0, stream>>>(user_idx, item_idx, adj,
                                        user_tab, item_tab, ent_tab,
                                        attn_W, attn_b, W1, b1, W2, b2,
                                        cW, cb, oW, ob, out, B);
  }
}

// Round 22
// 51.646 us; speedup vs baseline: 1.2923x; 1.0093x over previous
//
#include <hip/hip_runtime.h>

#define NN 50
#define D 64
#define GRP 10

typedef unsigned int uint32;
typedef unsigned short ushort16;

__device__ __forceinline__ float wave_sum64(float x) {
#pragma unroll
  for (int off = 32; off > 0; off >>= 1)
    x += __shfl_xor(x, off, 64);
  return x;
}

__device__ __forceinline__ float readlane_f(float v, int l) {
  return __uint_as_float(__builtin_amdgcn_readlane(__float_as_uint(v), l));
}

__device__ __forceinline__ ushort16 f32_to_bf16(float f) {
  uint32 u = __float_as_uint(f);
  u += 0x7FFF + ((u >> 16) & 1);          // round-to-nearest-even
  return (ushort16)(u >> 16);
}

// ==== PREP: blocks [0,pblocks) = ent_proj; blocks [pblocks,+16) = W2@cW fuse =
__global__ __launch_bounds__(256, 4) void kgat_prep(
    const float* __restrict__ ent_tab, const float* __restrict__ attn_W,
    float* __restrict__ proj, ushort16* __restrict__ ent_bf, int rows,
    int pblocks,
    const float* __restrict__ W2, const float* __restrict__ b2,
    const float* __restrict__ cW, const float* __restrict__ cb,
    float* __restrict__ W2cW, float* __restrict__ cb2)
{
  const int lane = threadIdx.x & 63;
  const int wv   = threadIdx.x >> 6;

  if ((int)blockIdx.x < pblocks) {
    const long wave = (long)blockIdx.x * 4 + wv;
    const long base = wave * GRP;
    if (base >= rows) return;
    const float Wn = attn_W[D + lane];
    float v[GRP];
#pragma unroll
    for (int i = 0; i < GRP; ++i) {
      long r = base + i; if (r > rows - 1) r = rows - 1;
      v[i] = ent_tab[r * D + lane];         // coalesced, contiguous rows
    }
    float s[GRP];
#pragma unroll
    for (int i = 0; i < GRP; ++i)
      s[i] = wave_sum64(v[i] * Wn);         // 10 independent butterfly chains
#pragma unroll
    for (int i = 0; i < GRP; ++i) {
      const long r = base + i;
      if (r < rows) ent_bf[r * D + lane] = f32_to_bf16(v[i]);
    }
    if (lane == 0) {
#pragma unroll
      for (int i = 0; i < GRP; ++i)
        if (base + i < rows) proj[base + i] = s[i];
    }
  } else {
    // weight fusion: W2cW = W2 @ cW_bot; cb2 = cb + b2 @ cW_bot
    const int d = ((int)blockIdx.x - pblocks) * 4 + wv;   // 0..63
    float acc = 0.f;
#pragma unroll 8
    for (int k = 0; k < D; ++k)
      acc = fmaf(W2[d * D + k], cW[(D + k) * D + lane], acc);
    W2cW[d * D + lane] = acc;
    if (d == 0) {
      float a2 = 0.f;
#pragma unroll 8
      for (int k = 0; k < D; ++k)
        a2 = fmaf(b2[k], cW[(D + k) * D + lane], a2);
      cb2[lane] = cb[lane] + a2;
    }
  }
}

// ===== A: attention, paired-row gathers (R20-proven, 2 rows / wave-load) ====
#define PGRP 5

__device__ __forceinline__ void load_pair_grp(uint32 (&buf)[PGRP],
                                              const int* __restrict__ adjb,
                                              const uint32* __restrict__ ent32,
                                              int g, int half, int sub) {
#pragma unroll
  for (int i = 0; i < PGRP; ++i) {
    const int p = g * PGRP + i;
    int t0 = adjb[2 * p + 0]; t0 = t0 < 0 ? 0 : t0;
    int t1 = adjb[2 * p + 1]; t1 = t1 < 0 ? 0 : t1;
    const int t = half ? t1 : t0;
    buf[i] = ent32[(size_t)t * 32 + sub];   // 4B/lane, 2 rows per instruction
  }
}

__device__ __forceinline__ void acc_pair_grp(const uint32 (&buf)[PGRP],
                                             float e, int g, int half,
                                             float& lo0, float& lo1,
                                             float& hi0, float& hi1) {
#pragma unroll
  for (int i = 0; i < PGRP; ++i) {
    const int p = g * PGRP + i;
    const float w0 = readlane_f(e, 2 * p + 0);
    const float w1 = readlane_f(e, 2 * p + 1);
    const float w  = half ? w1 : w0;
    const float lo = __uint_as_float(buf[i] << 16);          // bf16 dim 2*sub
    const float hi = __uint_as_float(buf[i] & 0xFFFF0000u);  // bf16 dim 2*sub+1
    if (i & 1) { lo1 = fmaf(w, lo, lo1); hi1 = fmaf(w, hi, hi1); }
    else       { lo0 = fmaf(w, lo, lo0); hi0 = fmaf(w, hi, hi0); }
  }
}

__global__ __launch_bounds__(256, 4) void kgat_attn2(
    const int* __restrict__ item_idx, const int* __restrict__ adj,
    const float* __restrict__ item_tab,
    const uint32* __restrict__ ent32, const float* __restrict__ proj,
    const float* __restrict__ attn_W, const float* __restrict__ attn_b,
    float* __restrict__ naws, int B)
{
  const int lane = threadIdx.x & 63;
  const int wv   = threadIdx.x >> 6;
  const int b    = blockIdx.x * 4 + wv;
  if (b >= B) return;
  const int half = lane >> 5;
  const int sub  = lane & 31;

  const int* adjb = adj + (long)b * NN;

  uint32 GA[PGRP], GB[PGRP];
  load_pair_grp(GA, adjb, ent32, 0, half, sub);
  load_pair_grp(GB, adjb, ent32, 1, half, sub);

  const float item = item_tab[(long)item_idx[b] * D + lane];
  const float base = wave_sum64(item * attn_W[lane]) + attn_b[0];  // uniform

  const int myn = lane < NN ? lane : NN - 1;
  int mi = adjb[myn]; mi = mi < 0 ? 0 : mi;
  float s = proj[mi] + base;
  s = s > 0.f ? s : 0.2f * s;                     // leaky_relu(0.2)
  // scores are leaky_relu of ~unit-variance dots, bounded well below 8 ->
  // exp(s-8) can't overflow, denom can't underflow to 0.
  const float e = (lane < NN) ? __expf(s - 8.0f) : 0.f;
  const float denom = wave_sum64(e);

  float lo0 = 0.f, lo1 = 0.f, hi0 = 0.f, hi1 = 0.f;
  acc_pair_grp(GA, e, 0, half, lo0, lo1, hi0, hi1);
  load_pair_grp(GA, adjb, ent32, 2, half, sub);
  acc_pair_grp(GB, e, 1, half, lo0, lo1, hi0, hi1);
  load_pair_grp(GB, adjb, ent32, 3, half, sub);
  acc_pair_grp(GA, e, 2, half, lo0, lo1, hi0, hi1);
  load_pair_grp(GA, adjb, ent32, 4, half, sub);
  acc_pair_grp(GB, e, 3, half, lo0, lo1, hi0, hi1);
  acc_pair_grp(GA, e, 4, half, lo0, lo1, hi0, hi1);

  float nlo = lo0 + lo1;
  float nhi = hi0 + hi1;
  nlo += __shfl_xor(nlo, 32, 64);
  nhi += __shfl_xor(nhi, 32, 64);

  const float inv = 1.0f / denom;
  if (lane < 32) {                                 // coalesced float2 store
    float2 val = make_float2(nlo * inv, nhi * inv);
    *(float2*)(naws + (long)b * D + 2 * sub) = val;
  }
}

// ===== M: fused MLP; phase A merges na@W1 with item@cW (independent) ========
// f = relu( item@cW_top + h@W2cW + cb2 ), h = relu(na@W1 + b1)
__global__ __launch_bounds__(256, 4) void kgat_mlpf(
    const int* __restrict__ user_idx, const int* __restrict__ item_idx,
    const float* __restrict__ user_tab, const float* __restrict__ item_tab,
    const float* __restrict__ naws,
    const float* __restrict__ W1, const float* __restrict__ b1,
    const float* __restrict__ cW,
    const float* __restrict__ W2cW, const float* __restrict__ cb2,
    const float* __restrict__ oW, const float* __restrict__ ob,
    float* __restrict__ out, int B)
{
  __shared__ __align__(16) float s_h[4 * 4 * D];   // h broadcast (4 elem/wave)

  const int lane = threadIdx.x & 63;
  const int wv   = threadIdx.x >> 6;
  const int b0   = (blockIdx.x * 4 + wv) * 4;
  if (b0 >= B) return;

  float* shA = s_h + (wv * 4 + 0) * D;
  float* shB = s_h + (wv * 4 + 1) * D;
  float* shC = s_h + (wv * 4 + 2) * D;
  float* shD = s_h + (wv * 4 + 3) * D;

  const int bA = b0 + 0 < B ? b0 + 0 : B - 1;
  const int bB = b0 + 1 < B ? b0 + 1 : B - 1;
  const int bC = b0 + 2 < B ? b0 + 2 : B - 1;
  const int bD = b0 + 3 < B ? b0 + 3 : B - 1;

  // wave-uniform activation bases -> scalar-pipe loads (s_load_dwordx4)
  const int uA = __builtin_amdgcn_readfirstlane(bA);
  const int uB = __builtin_amdgcn_readfirstlane(bB);
  const int uC = __builtin_amdgcn_readfirstlane(bC);
  const int uD = __builtin_amdgcn_readfirstlane(bD);
  const float* napA = naws + (long)uA * D;
  const float* napB = naws + (long)uB * D;
  const float* napC = naws + (long)uC * D;
  const float* napD = naws + (long)uD * D;
  const int iiA = __builtin_amdgcn_readfirstlane(item_idx[bA]);
  const int iiB = __builtin_amdgcn_readfirstlane(item_idx[bB]);
  const int iiC = __builtin_amdgcn_readfirstlane(item_idx[bC]);
  const int iiD = __builtin_amdgcn_readfirstlane(item_idx[bD]);
  const float* itpA = item_tab + (long)iiA * D;
  const float* itpB = item_tab + (long)iiB * D;
  const float* itpC = item_tab + (long)iiC * D;
  const float* itpD = item_tab + (long)iiD * D;

  // user rows per-lane (lane = dim), coalesced
  const float usA = user_tab[(long)user_idx[bA] * D + lane];
  const float usB = user_tab[(long)user_idx[bB] * D + lane];
  const float usC = user_tab[(long)user_idx[bC] * D + lane];
  const float usD = user_tab[(long)user_idx[bD] * D + lane];

  // ---- phase A (merged): h-acc = na@W1 + b1  AND  f-acc = item@cW + cb2.
  //      The two sides are independent -> 2x independent work per scalar-load
  //      stall point (hides the s_load LLC latency that serial loops exposed).
  const float b1v  = b1[lane];
  const float cb2v = cb2[lane];
  float hA0 = b1v, hA1 = 0.f, hB0 = b1v, hB1 = 0.f;
  float hC0 = b1v, hC1 = 0.f, hD0 = b1v, hD1 = 0.f;
  float fA0 = cb2v, fA1 = 0.f, fB0 = cb2v, fB1 = 0.f;
  float fC0 = cb2v, fC1 = 0.f, fD0 = cb2v, fD1 = 0.f;
#pragma unroll
  for (int d = 0; d < D; d += 4) {
    const float v0 = W1[(d + 0) * D + lane];
    const float v1 = W1[(d + 1) * D + lane];
    const float v2 = W1[(d + 2) * D + lane];
    const float v3 = W1[(d + 3) * D + lane];
    const float w0 = cW[(d + 0) * D + lane];
    const float w1 = cW[(d + 1) * D + lane];
    const float w2 = cW[(d + 2) * D + lane];
    const float w3 = cW[(d + 3) * D + lane];
    const float4 aA = *(const float4*)(napA + d);
    const float4 aB = *(const float4*)(napB + d);
    const float4 aC = *(const float4*)(napC + d);
    const float4 aD = *(const float4*)(napD + d);
    const float4 iA = *(const float4*)(itpA + d);
    const float4 iB = *(const float4*)(itpB + d);
    const float4 iC = *(const float4*)(itpC + d);
    const float4 iD = *(const float4*)(itpD + d);
    hA0 = fmaf(aA.x, v0, hA0); hA1 = fmaf(aA.y, v1, hA1);
    hA0 = fmaf(aA.z, v2, hA0); hA1 = fmaf(aA.w, v3, hA1);
    hB0 = fmaf(aB.x, v0, hB0); hB1 = fmaf(aB.y, v1, hB1);
    hB0 = fmaf(aB.z, v2, hB0); hB1 = fmaf(aB.w, v3, hB1);
    hC0 = fmaf(aC.x, v0, hC0); hC1 = fmaf(aC.y, v1, hC1);
    hC0 = fmaf(aC.z, v2, hC0); hC1 = fmaf(aC.w, v3, hC1);
    hD0 = fmaf(aD.x, v0, hD0); hD1 = fmaf(aD.y, v1, hD1);
    hD0 = fmaf(aD.z, v2, hD0); hD1 = fmaf(aD.w, v3, hD1);
    fA0 = fmaf(iA.x, w0, fA0); fA1 = fmaf(iA.y, w1, fA1);
    fA0 = fmaf(iA.z, w2, fA0); fA1 = fmaf(iA.w, w3, fA1);
    fB0 = fmaf(iB.x, w0, fB0); fB1 = fmaf(iB.y, w1, fB1);
    fB0 = fmaf(iB.z, w2, fB0); fB1 = fmaf(iB.w, w3, fB1);
    fC0 = fmaf(iC.x, w0, fC0); fC1 = fmaf(iC.y, w1, fC1);
    fC0 = fmaf(iC.z, w2, fC0); fC1 = fmaf(iC.w, w3, fC1);
    fD0 = fmaf(iD.x, w0, fD0); fD1 = fmaf(iD.y, w1, fD1);
    fD0 = fmaf(iD.z, w2, fD0); fD1 = fmaf(iD.w, w3, fD1);
  }
  shA[lane] = fmaxf(hA0 + hA1, 0.f);               // wave-private, no barrier
  shB[lane] = fmaxf(hB0 + hB1, 0.f);
  shC[lane] = fmaxf(hC0 + hC1, 0.f);
  shD[lane] = fmaxf(hD0 + hD1, 0.f);

  // ---- phase B: f += h @ W2cW (h via LDS broadcast) ----
#pragma unroll
  for (int d = 0; d < D; d += 4) {
    const float w0 = W2cW[(d + 0) * D + lane];
    const float w1 = W2cW[(d + 1) * D + lane];
    const float w2 = W2cW[(d + 2) * D + lane];
    const float w3 = W2cW[(d + 3) * D + lane];
    const float4 cA = *(const float4*)(shA + d);
    const float4 cB = *(const float4*)(shB + d);
    const float4 cC = *(const float4*)(shC + d);
    const float4 cD = *(const float4*)(shD + d);
    fA0 = fmaf(cA.x, w0, fA0); fA1 = fmaf(cA.y, w1, fA1);
    fA0 = fmaf(cA.z, w2, fA0); fA1 = fmaf(cA.w, w3, fA1);
    fB0 = fmaf(cB.x, w0, fB0); fB1 = fmaf(cB.y, w1, fB1);
    fB0 = fmaf(cB.z, w2, fB0); fB1 = fmaf(cB.w, w3, fB1);
    fC0 = fmaf(cC.x, w0, fC0); fC1 = fmaf(cC.y, w1, fC1);
    fC0 = fmaf(cC.z, w2, fC0); fC1 = fmaf(cC.w, w3, fC1);
    fD0 = fmaf(cD.x, w0, fD0); fD1 = fmaf(cD.y, w1, fD1);
    fD0 = fmaf(cD.z, w2, fD0); fD1 = fmaf(cD.w, w3, fD1);
  }
  const float fA = fmaxf(fA0 + fA1, 0.f);
  const float fB = fmaxf(fB0 + fB1, 0.f);
  const float fC = fmaxf(fC0 + fC1, 0.f);
  const float fD = fmaxf(fD0 + fD1, 0.f);

  // ---- score = dot([user, f], oW) + ob ----
  const float oWu = oW[lane];
  const float oWf = oW[D + lane];
  const float ob0 = ob[0];
  const float scA = wave_sum64(fmaf(usA, oWu, fA * oWf));
  const float scB = wave_sum64(fmaf(usB, oWu, fB * oWf));
  const float scC = wave_sum64(fmaf(usC, oWu, fC * oWf));
  const float scD = wave_sum64(fmaf(usD, oWu, fD * oWf));
  if (lane == 0) {
    out[bA] = scA + ob0;
    if (bB != bA) out[bB] = scB + ob0;
    if (bC != bB) out[bC] = scC + ob0;
    if (bD != bC) out[bD] = scD + ob0;
  }
}

// ================= fallback: exact R3 kernel (small/no workspace) ===========
__device__ __forceinline__ void load_grp(float (&buf)[GRP],
                                         const int* __restrict__ adjb,
                                         const float* __restrict__ ent_tab,
                                         int g, int lane) {
#pragma unroll
  for (int i = 0; i < GRP; ++i) {
    int t = adjb[g * GRP + i];
    t = t < 0 ? 0 : t;
    buf[i] = ent_tab[(long)t * D + lane];
  }
}

__device__ __forceinline__ void proc_grp(const float (&buf)[GRP],
                                         float Wn, float base,
                                         float& l0, float& l1, float& na) {
  float ex[GRP];
#pragma unroll
  for (int i = 0; i < GRP; ++i) {
    float t = wave_sum64(buf[i] * Wn) + base;
    t = t > 0.f ? t : 0.2f * t;
    ex[i] = __expf(t - 8.0f);
  }
#pragma unroll
  for (int i = 0; i < GRP; ++i) {
    if (i & 1) l1 += ex[i]; else l0 += ex[i];
    na = fmaf(ex[i], buf[i], na);
  }
}

__global__ __launch_bounds__(256, 4) void kgat_r3(
    const int* __restrict__ user_idx, const int* __restrict__ item_idx,
    const int* __restrict__ adj,
    const float* __restrict__ user_tab, const float* __restrict__ item_tab,
    const float* __restrict__ ent_tab,
    const float* __restrict__ attn_W, const float* __restrict__ attn_b,
    const float* __restrict__ W1, const float* __restrict__ b1,
    const float* __restrict__ W2, const float* __restrict__ b2,
    const float* __restrict__ cW, const float* __restrict__ cb,
    const float* __restrict__ oW, const float* __restrict__ ob,
    float* __restrict__ out, int B)
{
  const int lane = threadIdx.x & 63;
  const int wv   = threadIdx.x >> 6;
  const int b    = blockIdx.x * 4 + wv;
  if (b >= B) return;

  const float user = user_tab[(long)user_idx[b] * D + lane];
  const float oWu  = oW[lane];
  const float oWf  = oW[D + lane];
  const float item = item_tab[(long)item_idx[b] * D + lane];
  const float Wi   = attn_W[lane];
  const float Wn   = attn_W[D + lane];
  const float base = wave_sum64(item * Wi) + attn_b[0];
  const int* adjb = adj + b * NN;

  float na = 0.f, l0 = 0.f, l1 = 0.f;
  float A[GRP], Bv[GRP];
  load_grp(A,  adjb, ent_tab, 0, lane);
  load_grp(Bv, adjb, ent_tab, 1, lane);
  proc_grp(A,  Wn, base, l0, l1, na);
  load_grp(A,  adjb, ent_tab, 2, lane);
  proc_grp(Bv, Wn, base, l0, l1, na);
  load_grp(Bv, adjb, ent_tab, 3, lane);
  proc_grp(A,  Wn, base, l0, l1, na);
  load_grp(A,  adjb, ent_tab, 4, lane);
  proc_grp(Bv, Wn, base, l0, l1, na);
  proc_grp(A,  Wn, base, l0, l1, na);
  na /= (l0 + l1);

  float h0 = b1[lane], h1 = 0.f, h2 = 0.f, h3 = 0.f;
#pragma unroll
  for (int d = 0; d < D; d += 4) {
    h0 = fmaf(readlane_f(na, d + 0), W1[(d + 0) * D + lane], h0);
    h1 = fmaf(readlane_f(na, d + 1), W1[(d + 1) * D + lane], h1);
    h2 = fmaf(readlane_f(na, d + 2), W1[(d + 2) * D + lane], h2);
    h3 = fmaf(readlane_f(na, d + 3), W1[(d + 3) * D + lane], h3);
  }
  const float h = fmaxf((h0 + h1) + (h2 + h3), 0.f);

  float r0 = b2[lane], r1 = 0.f, r2 = 0.f, r3 = 0.f;
#pragma unroll
  for (int d = 0; d < D; d += 4) {
    r0 = fmaf(readlane_f(h, d + 0), W2[(d + 0) * D + lane], r0);
    r1 = fmaf(readlane_f(h, d + 1), W2[(d + 1) * D + lane], r1);
    r2 = fmaf(readlane_f(h, d + 2), W2[(d + 2) * D + lane], r2);
    r3 = fmaf(readlane_f(h, d + 3), W2[(d + 3) * D + lane], r3);
  }
  const float r = (r0 + r1) + (r2 + r3);

  float f0 = cb[lane], f1 = 0.f, f2 = 0.f, f3 = 0.f;
#pragma unroll
  for (int k = 0; k < D; k += 4) {
    f0 = fmaf(readlane_f(item, k + 0), cW[(k + 0) * D + lane], f0);
    f1 = fmaf(readlane_f(item, k + 1), cW[(k + 1) * D + lane], f1);
    f2 = fmaf(readlane_f(item, k + 2), cW[(k + 2) * D + lane], f2);
    f3 = fmaf(readlane_f(item, k + 3), cW[(k + 3) * D + lane], f3);
  }
#pragma unroll
  for (int k = 0; k < D; k += 4) {
    f0 = fmaf(readlane_f(r, k + 0), cW[(D + k + 0) * D + lane], f0);
    f1 = fmaf(readlane_f(r, k + 1), cW[(D + k + 1) * D + lane], f1);
    f2 = fmaf(readlane_f(r, k + 2), cW[(D + k + 2) * D + lane], f2);
    f3 = fmaf(readlane_f(r, k + 3), cW[(D + k + 3) * D + lane], f3);
  }
  const float f = fmaxf((f0 + f1) + (f2 + f3), 0.f);

  const float sc = wave_sum64(fmaf(user, oWu, f * oWf));
  if (lane == 0) out[b] = sc + ob[0];
}

extern "C" void kernel_launch(void* const* d_in, const int* in_sizes, int n_in,
                              void* d_out, int out_size, void* d_ws, size_t ws_size,
                              hipStream_t stream) {
  const int*   user_idx = (const int*)d_in[0];
  const int*   item_idx = (const int*)d_in[1];
  const int*   adj      = (const int*)d_in[2];
  const float* user_tab = (const float*)d_in[3];
  const float* item_tab = (const float*)d_in[4];
  const float* ent_tab  = (const float*)d_in[5];
  const float* attn_W   = (const float*)d_in[6];
  const float* attn_b   = (const float*)d_in[7];
  const float* W1       = (const float*)d_in[8];
  const float* b1       = (const float*)d_in[9];
  const float* W2       = (const float*)d_in[10];
  const float* b2       = (const float*)d_in[11];
  const float* cW       = (const float*)d_in[12];
  const float* cb       = (const float*)d_in[13];
  const float* oW       = (const float*)d_in[14];
  const float* ob       = (const float*)d_in[15];
  float* out = (float*)d_out;

  const int B    = in_sizes[0];
  const int rows = in_sizes[5] / D;               // entity count

  // ws layout: [proj f32][ent_bf bf16][naws f32][W2cW f32][cb2 f32]
  const size_t off_bf = ((size_t)rows * 4 + 255) & ~(size_t)255;
  const size_t off_na = (off_bf + (size_t)rows * D * 2 + 255) & ~(size_t)255;
  const size_t off_w2 = (off_na + (size_t)B * D * 4 + 255) & ~(size_t)255;
  const size_t off_cb = off_w2 + (size_t)D * D * 4;
  const size_t need   = off_cb + (size_t)D * 4;

  if (ws_size >= need) {
    float*    proj   = (float*)d_ws;
    ushort16* ent_bf = (ushort16*)((char*)d_ws + off_bf);
    float*    naws   = (float*)((char*)d_ws + off_na);
    float*    W2cW   = (float*)((char*)d_ws + off_w2);
    float*    cb2    = (float*)((char*)d_ws + off_cb);
    const int waves   = (rows + GRP - 1) / GRP;
    const int pblocks = (waves + 3) / 4;
    const int ablocks = (B + 3) / 4;              // attention: 1 elem/wave
    const int mblocks = (B + 15) / 16;            // MLP: 4 elems/wave
    kgat_prep<<<pblocks + 16, 256, 0, stream>>>(ent_tab, attn_W, proj, ent_bf,
                                                rows, pblocks, W2, b2, cW, cb,
                                                W2cW, cb2);
    kgat_attn2<<<ablocks, 256, 0, stream>>>(item_idx, adj, item_tab,
                                            (const uint32*)ent_bf, proj,
                                            attn_W, attn_b, naws, B);
    kgat_mlpf<<<mblocks, 256, 0, stream>>>(user_idx, item_idx, user_tab,
                                           item_tab, naws, W1, b1, cW,
                                           W2cW, cb2, oW, ob, out, B);
  } else {
    const int blocks = (B + 3) / 4;
    kgat_r3<<<blocks, 256, 0, stream>>>(user_idx, item_idx, adj,
                                        user_tab, item_tab, ent_tab,
                                        attn_W, attn_b, W1, b1, W2, b2,
                                        cW, cb, oW, ob, out, B);
  }
}